// Round 2
// baseline (323.216 us; speedup 1.0000x reference)
//
#include <hip/hip_runtime.h>
#include <hip/hip_bf16.h>

#define B_  2
#define S_  512
#define H_  8
#define D_  32
#define DM_ 256
#define HD_ 256
#define NROW 4
#define NW  8          // waves per attention block (512 threads)

// ---------------------------------------------------------------------------
// Kernel A: QKV projection.  grid = (B*S/NROW, 3), block = 256.
// out layout: (b, h, s, d).  q is pre-scaled by 1/sqrt(D).
// ---------------------------------------------------------------------------
__global__ __launch_bounds__(256) void qkv_kernel(
    const float* __restrict__ hid, const float* __restrict__ wq,
    const float* __restrict__ wk, const float* __restrict__ wv,
    float* __restrict__ qo, float* __restrict__ ko, float* __restrict__ vo)
{
  __shared__ __align__(16) float hs[NROW][DM_];
  const int r0 = blockIdx.x * NROW;                 // global row in [0, B*S)
  const float* w   = (blockIdx.y == 0) ? wq : (blockIdx.y == 1) ? wk : wv;
  float*       out = (blockIdx.y == 0) ? qo : (blockIdx.y == 1) ? ko : vo;
  const float mulf = (blockIdx.y == 0) ? 0.17677669529663687f : 1.0f;
  const int tid = threadIdx.x;

  for (int idx = tid; idx < NROW * DM_; idx += 256)
    hs[idx >> 8][idx & 255] = hid[r0 * DM_ + idx];
  __syncthreads();

  float acc[NROW] = {0.f, 0.f, 0.f, 0.f};
  const float* wp = w + tid;                        // column m = tid
  #pragma unroll 8
  for (int c4 = 0; c4 < DM_ / 4; ++c4) {
    const float w0 = wp[(4 * c4 + 0) * HD_];
    const float w1 = wp[(4 * c4 + 1) * HD_];
    const float w2 = wp[(4 * c4 + 2) * HD_];
    const float w3 = wp[(4 * c4 + 3) * HD_];
    #pragma unroll
    for (int r = 0; r < NROW; ++r) {
      const float4 hv = reinterpret_cast<const float4*>(&hs[r][0])[c4];
      acc[r] = fmaf(hv.x, w0, acc[r]);
      acc[r] = fmaf(hv.y, w1, acc[r]);
      acc[r] = fmaf(hv.z, w2, acc[r]);
      acc[r] = fmaf(hv.w, w3, acc[r]);
    }
  }
  const int h = tid >> 5, d = tid & 31;
  #pragma unroll
  for (int r = 0; r < NROW; ++r) {
    const int g = r0 + r;
    const int b = g >> 9, s = g & (S_ - 1);
    out[((b * H_ + h) * S_ + s) * D_ + d] = acc[r] * mulf;
  }
}

// 4-lane (quad) butterfly sum via DPP: all 4 lanes of the quad get the sum.
__device__ __forceinline__ float red4(float x) {
  int i;
  i = __builtin_amdgcn_mov_dpp(__float_as_int(x), 0xB1, 0xf, 0xf, true); // quad_perm xor1
  x += __int_as_float(i);
  i = __builtin_amdgcn_mov_dpp(__float_as_int(x), 0x4E, 0xf, 0xf, true); // quad_perm xor2
  x += __int_as_float(i);
  return x;
}

// ---------------------------------------------------------------------------
// Kernel B (fused): scores + mask + softmax + attn@V + fc + residual + LN.
// One block per (b, i): grid = B*S = 1024, block = 512 (8 waves).
// R1 post-mortem: 256-thread version was latency-bound (VALUBusy 25%,
// HBM 7%, L2 37%, Occupancy 34% -> classic exposed-L2-latency at 16
// waves/CU).  8 waves x 4 blocks/CU = 32 waves/CU (HW max) doubles the
// latency hiding with IDENTICAL traffic and LDS footprint (18.5 KB -> 4
// blocks/CU still fits).  rpe row (b,i,:,:) still read exactly once.
// Score mapping: lane=(j4,dq), 4 dq-lanes cover one j's 128B d-row (32B each).
// attn@V mapping: lane=(j8,dc), dc*16B slice.
// scores[h,j] = sum_d q'[h,j,d] k[h,i,d] rpe[i,j,d]  (q' pre-scaled);
// mask: j < station OR j == i.
// NOTE: register arrays use compile-time indices ONLY (dynamic index ->
// scratch demotion -> spill traffic).
// ---------------------------------------------------------------------------
__global__ __launch_bounds__(512, 8) void attn_fused_kernel(
    const float* __restrict__ rpe, const float* __restrict__ q_ws,
    const float* __restrict__ k_ws, const float* __restrict__ v_ws,
    const int* __restrict__ station_p, const float* __restrict__ fc_w,
    const float* __restrict__ fc_b, const float* __restrict__ hid,
    const float* __restrict__ ln_w, const float* __restrict__ ln_b,
    float* __restrict__ out)
{
  __shared__ __align__(16) float p_smem[H_ * S_];   // 16 KB; reused as redv
  __shared__ __align__(16) float ks[H_ * D_];       // 1 KB K row, 8 heads
  __shared__ __align__(16) float orow[HD_];         // 1 KB attention output row
  __shared__ float sums[H_];
  __shared__ float redm[4];
  __shared__ float redvr[4];

  const int tid  = threadIdx.x;
  const int w    = tid >> 6, lane = tid & 63;
  const int j4   = lane >> 2, dq = lane & 3;        // score mapping
  const int j8   = lane >> 3, dc = lane & 7;        // attn@V mapping
  const int n    = blockIdx.x;                      // 0..1023
  const int b    = n >> 9;
  const int i    = n & (S_ - 1);
  const int HS   = S_ * D_;                         // head stride

  int station = station_p[0];
  station = station > S_ ? S_ : (station < 0 ? 0 : station);

  const float* qb = q_ws + (size_t)(b * H_) * S_ * D_;
  const float* kb = k_ws + (size_t)(b * H_) * S_ * D_;
  const float* vb = v_ws + (size_t)(b * H_) * S_ * D_;
  const float* rb = rpe + ((size_t)b * S_ + i) * S_ * D_;

  // stage K row i for all 8 heads into LDS
  if (tid < H_ * D_) {
    const int h = tid >> 5, d = tid & 31;
    ks[tid] = kb[h * HS + i * D_ + d];
  }
  __syncthreads();

  // ---- scores: wave w covers j in {w*16 + pass*128 + j4} ----
  for (int jb = w * 16; jb < station; jb += NW * 16) {
    const int j  = jb + j4;
    const int jc = j < S_ ? j : S_ - 1;
    const float4 r0 = *reinterpret_cast<const float4*>(rb + jc * D_ + dq * 8);
    const float4 r1 = *reinterpret_cast<const float4*>(rb + jc * D_ + dq * 8 + 4);
    #pragma unroll
    for (int hh = 0; hh < H_; ++hh) {
      const float4 q0 = *reinterpret_cast<const float4*>(qb + hh * HS + jc * D_ + dq * 8);
      const float4 q1 = *reinterpret_cast<const float4*>(qb + hh * HS + jc * D_ + dq * 8 + 4);
      const float4 k0 = *reinterpret_cast<const float4*>(&ks[hh * D_ + dq * 8]);
      const float4 k1 = *reinterpret_cast<const float4*>(&ks[hh * D_ + dq * 8 + 4]);
      float s = q0.x * k0.x * r0.x;
      s = fmaf(q0.y * k0.y, r0.y, s);
      s = fmaf(q0.z * k0.z, r0.z, s);
      s = fmaf(q0.w * k0.w, r0.w, s);
      s = fmaf(q1.x * k1.x, r1.x, s);
      s = fmaf(q1.y * k1.y, r1.y, s);
      s = fmaf(q1.z * k1.z, r1.z, s);
      s = fmaf(q1.w * k1.w, r1.w, s);
      s = red4(s);
      if (dq == 0 && j < station) p_smem[hh * S_ + j] = s;
    }
  }
  // diagonal cell j == i when i >= station (wave 0, lanes 0..3 = one quad)
  if (w == 0 && j4 == 0 && i >= station) {
    const float4 r0 = *reinterpret_cast<const float4*>(rb + i * D_ + dq * 8);
    const float4 r1 = *reinterpret_cast<const float4*>(rb + i * D_ + dq * 8 + 4);
    #pragma unroll
    for (int hh = 0; hh < H_; ++hh) {
      const float4 q0 = *reinterpret_cast<const float4*>(qb + hh * HS + i * D_ + dq * 8);
      const float4 q1 = *reinterpret_cast<const float4*>(qb + hh * HS + i * D_ + dq * 8 + 4);
      const float4 k0 = *reinterpret_cast<const float4*>(&ks[hh * D_ + dq * 8]);
      const float4 k1 = *reinterpret_cast<const float4*>(&ks[hh * D_ + dq * 8 + 4]);
      float s = q0.x * k0.x * r0.x;
      s = fmaf(q0.y * k0.y, r0.y, s);
      s = fmaf(q0.z * k0.z, r0.z, s);
      s = fmaf(q0.w * k0.w, r0.w, s);
      s = fmaf(q1.x * k1.x, r1.x, s);
      s = fmaf(q1.y * k1.y, r1.y, s);
      s = fmaf(q1.z * k1.z, r1.z, s);
      s = fmaf(q1.w * k1.w, r1.w, s);
      s = red4(s);
      if (dq == 0) p_smem[hh * S_ + i] = s;
    }
  }
  __syncthreads();

  // ---- softmax: wave w handles head row w (NW == H_ == 8) ----
  const bool dx = (i >= station);
  {
    const int r = w;
    float m = -1e30f;
    for (int jj = lane; jj < station; jj += 64) m = fmaxf(m, p_smem[r * S_ + jj]);
    const float dv = dx ? p_smem[r * S_ + i] : -1e30f;
    m = fmaxf(m, dv);
    #pragma unroll
    for (int o = 32; o; o >>= 1) m = fmaxf(m, __shfl_xor(m, o, 64));
    float sum = 0.f;
    for (int jj = lane; jj < station; jj += 64) {
      const float e = __expf(p_smem[r * S_ + jj] - m);
      p_smem[r * S_ + jj] = e;
      sum += e;
    }
    #pragma unroll
    for (int o = 32; o; o >>= 1) sum += __shfl_xor(sum, o, 64);
    if (dx) {
      const float e = __expf(dv - m);
      sum += e;
      if (lane == 0) p_smem[r * S_ + i] = e;
    }
    if (lane == 0) sums[r] = sum;
  }
  __syncthreads();

  // ---- attn @ V: thread (j8,dc) accumulates its j-slice, all 8 heads ----
  float4 acc[H_];
  #pragma unroll
  for (int hh = 0; hh < H_; ++hh) acc[hh] = make_float4(0.f, 0.f, 0.f, 0.f);

  for (int jb = w * 8; jb < station; jb += NW * 8) {
    const int j  = jb + j8;
    const int jc = j < S_ ? j : S_ - 1;
    #pragma unroll
    for (int hh = 0; hh < H_; ++hh) {
      const float4 v4 = *reinterpret_cast<const float4*>(vb + hh * HS + jc * D_ + dc * 4);
      float pv = 0.f;
      if (j < station) pv = p_smem[hh * S_ + j];
      acc[hh].x = fmaf(pv, v4.x, acc[hh].x);
      acc[hh].y = fmaf(pv, v4.y, acc[hh].y);
      acc[hh].z = fmaf(pv, v4.z, acc[hh].z);
      acc[hh].w = fmaf(pv, v4.w, acc[hh].w);
    }
  }
  // diagonal contribution (exactly once: wave 0, j8==0 lanes)
  if (w == 0 && j8 == 0 && dx) {
    #pragma unroll
    for (int hh = 0; hh < H_; ++hh) {
      const float pv = p_smem[hh * S_ + i];
      const float4 v4 = *reinterpret_cast<const float4*>(vb + hh * HS + i * D_ + dc * 4);
      acc[hh].x = fmaf(pv, v4.x, acc[hh].x);
      acc[hh].y = fmaf(pv, v4.y, acc[hh].y);
      acc[hh].z = fmaf(pv, v4.z, acc[hh].z);
      acc[hh].w = fmaf(pv, v4.w, acc[hh].w);
    }
  }
  __syncthreads();   // p_smem reads done before reuse as redv

  // ---- reduce over (w, j8): shfl over j8 bits then LDS over 8 waves ----
  float4* redv = reinterpret_cast<float4*>(p_smem);   // 8 waves x 8 heads x 8 dc
  #pragma unroll
  for (int hh = 0; hh < H_; ++hh) {
    float4 a = acc[hh];
    #pragma unroll
    for (int o = 8; o <= 32; o <<= 1) {
      a.x += __shfl_xor(a.x, o, 64);
      a.y += __shfl_xor(a.y, o, 64);
      a.z += __shfl_xor(a.z, o, 64);
      a.w += __shfl_xor(a.w, o, 64);
    }
    if (j8 == 0) redv[(w * H_ + hh) * 8 + dc] = a;
  }
  __syncthreads();
  if (tid < H_ * 8) {
    const int r = tid >> 3, d4 = tid & 7;             // r = head
    float4 a = make_float4(0.f, 0.f, 0.f, 0.f);
    #pragma unroll
    for (int g = 0; g < NW; ++g) {
      const float4 x = redv[(g * H_ + r) * 8 + d4];
      a.x += x.x; a.y += x.y; a.z += x.z; a.w += x.w;
    }
    const float inv = 1.f / sums[r];
    orow[r * D_ + d4 * 4 + 0] = a.x * inv;
    orow[r * D_ + d4 * 4 + 1] = a.y * inv;
    orow[r * D_ + d4 * 4 + 2] = a.z * inv;
    orow[r * D_ + d4 * 4 + 3] = a.w * inv;
  }
  __syncthreads();

  // ---- fc (thread per output column m=tid, first 4 waves) + residual + LN --
  float fca = 0.f;
  if (tid < DM_) {
    const float* wp = fc_w + tid;
    #pragma unroll 8
    for (int n4 = 0; n4 < HD_ / 4; ++n4) {
      const float4 ov = reinterpret_cast<const float4*>(orow)[n4];
      fca = fmaf(ov.x, wp[(4 * n4 + 0) * DM_], fca);
      fca = fmaf(ov.y, wp[(4 * n4 + 1) * DM_], fca);
      fca = fmaf(ov.z, wp[(4 * n4 + 2) * DM_], fca);
      fca = fmaf(ov.w, wp[(4 * n4 + 3) * DM_], fca);
    }
    fca += fc_b[tid] + hid[(size_t)n * DM_ + tid];
    float s = fca;
    #pragma unroll
    for (int o = 32; o; o >>= 1) s += __shfl_xor(s, o, 64);
    if (lane == 0) redm[w] = s;
  }
  __syncthreads();
  const float mu = (redm[0] + redm[1] + redm[2] + redm[3]) * (1.f / DM_);
  const float dd = fca - mu;
  if (tid < DM_) {
    float s = dd * dd;
    #pragma unroll
    for (int o = 32; o; o >>= 1) s += __shfl_xor(s, o, 64);
    if (lane == 0) redvr[w] = s;
  }
  __syncthreads();
  if (tid < DM_) {
    const float var = (redvr[0] + redvr[1] + redvr[2] + redvr[3]) * (1.f / DM_);
    out[(size_t)n * DM_ + tid] = dd * rsqrtf(var + 1e-6f) * ln_w[tid] + ln_b[tid];
  }
}

// ---------------------------------------------------------------------------
extern "C" void kernel_launch(void* const* d_in, const int* in_sizes, int n_in,
                              void* d_out, int out_size, void* d_ws, size_t ws_size,
                              hipStream_t stream) {
  const float* hid = (const float*)d_in[0];
  const float* rpe = (const float*)d_in[1];
  const float* wq  = (const float*)d_in[2];
  const float* wk  = (const float*)d_in[3];
  const float* wv  = (const float*)d_in[4];
  const float* fcw = (const float*)d_in[5];
  const float* fcb = (const float*)d_in[6];
  const float* lnw = (const float*)d_in[7];
  const float* lnb = (const float*)d_in[8];
  const int* station = (const int*)d_in[9];
  float* out = (float*)d_out;

  const size_t per = (size_t)B_ * H_ * S_ * D_;   // 262144 floats
  float* q_ws = (float*)d_ws;
  float* k_ws = q_ws + per;
  float* v_ws = k_ws + per;

  dim3 gA(B_ * S_ / NROW, 3);
  qkv_kernel<<<gA, 256, 0, stream>>>(hid, wq, wk, wv, q_ws, k_ws, v_ws);
  attn_fused_kernel<<<B_ * S_, 512, 0, stream>>>(
      rpe, q_ws, k_ws, v_ws, station, fcw, fcb, hid, lnw, lnb, out);
}

// Round 3
// 271.870 us; speedup vs baseline: 1.1889x; 1.1889x over previous
//
#include <hip/hip_runtime.h>
#include <hip/hip_bf16.h>

#define B_  2
#define S_  512
#define H_  8
#define D_  32
#define DM_ 256
#define HD_ 256
#define NROW 4
#define NW  8          // waves per attention block (512 threads)

// ---------------------------------------------------------------------------
// Kernel A: QKV projection.  grid = (B*S/NROW, 3), block = 256.
// out layout: (b, h, s, d).  q is pre-scaled by 1/sqrt(D).
// ---------------------------------------------------------------------------
__global__ __launch_bounds__(256) void qkv_kernel(
    const float* __restrict__ hid, const float* __restrict__ wq,
    const float* __restrict__ wk, const float* __restrict__ wv,
    float* __restrict__ qo, float* __restrict__ ko, float* __restrict__ vo)
{
  __shared__ __align__(16) float hs[NROW][DM_];
  const int r0 = blockIdx.x * NROW;                 // global row in [0, B*S)
  const float* w   = (blockIdx.y == 0) ? wq : (blockIdx.y == 1) ? wk : wv;
  float*       out = (blockIdx.y == 0) ? qo : (blockIdx.y == 1) ? ko : vo;
  const float mulf = (blockIdx.y == 0) ? 0.17677669529663687f : 1.0f;
  const int tid = threadIdx.x;

  for (int idx = tid; idx < NROW * DM_; idx += 256)
    hs[idx >> 8][idx & 255] = hid[r0 * DM_ + idx];
  __syncthreads();

  float acc[NROW] = {0.f, 0.f, 0.f, 0.f};
  const float* wp = w + tid;                        // column m = tid
  #pragma unroll 8
  for (int c4 = 0; c4 < DM_ / 4; ++c4) {
    const float w0 = wp[(4 * c4 + 0) * HD_];
    const float w1 = wp[(4 * c4 + 1) * HD_];
    const float w2 = wp[(4 * c4 + 2) * HD_];
    const float w3 = wp[(4 * c4 + 3) * HD_];
    #pragma unroll
    for (int r = 0; r < NROW; ++r) {
      const float4 hv = reinterpret_cast<const float4*>(&hs[r][0])[c4];
      acc[r] = fmaf(hv.x, w0, acc[r]);
      acc[r] = fmaf(hv.y, w1, acc[r]);
      acc[r] = fmaf(hv.z, w2, acc[r]);
      acc[r] = fmaf(hv.w, w3, acc[r]);
    }
  }
  const int h = tid >> 5, d = tid & 31;
  #pragma unroll
  for (int r = 0; r < NROW; ++r) {
    const int g = r0 + r;
    const int b = g >> 9, s = g & (S_ - 1);
    out[((b * H_ + h) * S_ + s) * D_ + d] = acc[r] * mulf;
  }
}

// 4-lane (quad) butterfly sum via DPP: all 4 lanes of the quad get the sum.
__device__ __forceinline__ float red4(float x) {
  int i;
  i = __builtin_amdgcn_mov_dpp(__float_as_int(x), 0xB1, 0xf, 0xf, true); // quad_perm xor1
  x += __int_as_float(i);
  i = __builtin_amdgcn_mov_dpp(__float_as_int(x), 0x4E, 0xf, 0xf, true); // quad_perm xor2
  x += __int_as_float(i);
  return x;
}

// ---------------------------------------------------------------------------
// Kernel B (fused): scores + mask + softmax + attn@V + fc + residual + LN.
// One block per (b, i): grid = B*S = 1024, block = 512 (8 waves).
// R2 post-mortem: launch_bounds(512,8) with acc[8] float4 (32 VGPR live)
// forced spills -> 390 MB scratch traffic, 5x regression.  R3 keeps the
// 8-wave occupancy (grid supplies 32 waves/CU) but CUTS DEMAND: PV is one
// head per wave (acc = ONE float4), orow written directly after the j8
// shfl-reduce (16 KB redv pass deleted).  Score-loop transient demand
// ~50 VGPR fits the 64-reg budget without spilling.
// Score mapping: lane=(j4,dq), 4 dq-lanes cover one j's 128B d-row (32B each).
// attn@V mapping: lane=(j8,dc); wave w owns head w.
// scores[h,j] = sum_d q'[h,j,d] k[h,i,d] rpe[i,j,d]  (q' pre-scaled);
// mask: j < station OR j == i.
// NOTE: register arrays use compile-time indices ONLY (dynamic index ->
// scratch demotion -> spill traffic).
// ---------------------------------------------------------------------------
__global__ __launch_bounds__(512, 8) void attn_fused_kernel(
    const float* __restrict__ rpe, const float* __restrict__ q_ws,
    const float* __restrict__ k_ws, const float* __restrict__ v_ws,
    const int* __restrict__ station_p, const float* __restrict__ fc_w,
    const float* __restrict__ fc_b, const float* __restrict__ hid,
    const float* __restrict__ ln_w, const float* __restrict__ ln_b,
    float* __restrict__ out)
{
  __shared__ __align__(16) float p_smem[H_ * S_];   // 16 KB
  __shared__ __align__(16) float ks[H_ * D_];       // 1 KB K row, 8 heads
  __shared__ __align__(16) float orow[HD_];         // 1 KB attention output row
  __shared__ float sums[H_];
  __shared__ float redm[4];
  __shared__ float redvr[4];

  const int tid  = threadIdx.x;
  const int w    = tid >> 6, lane = tid & 63;
  const int j4   = lane >> 2, dq = lane & 3;        // score mapping
  const int j8   = lane >> 3, dc = lane & 7;        // attn@V mapping
  const int n    = blockIdx.x;                      // 0..1023
  const int b    = n >> 9;
  const int i    = n & (S_ - 1);
  const int HS   = S_ * D_;                         // head stride

  int station = station_p[0];
  station = station > S_ ? S_ : (station < 0 ? 0 : station);

  const float* qb = q_ws + (size_t)(b * H_) * S_ * D_;
  const float* kb = k_ws + (size_t)(b * H_) * S_ * D_;
  const float* vb = v_ws + (size_t)(b * H_) * S_ * D_;
  const float* rb = rpe + ((size_t)b * S_ + i) * S_ * D_;

  // stage K row i for all 8 heads into LDS
  if (tid < H_ * D_) {
    const int h = tid >> 5, d = tid & 31;
    ks[tid] = kb[h * HS + i * D_ + d];
  }
  __syncthreads();

  // ---- scores: wave w covers j in {w*16 + pass*128 + j4} ----
  for (int jb = w * 16; jb < station; jb += NW * 16) {
    const int j  = jb + j4;
    const int jc = j < S_ ? j : S_ - 1;
    const float4 r0 = *reinterpret_cast<const float4*>(rb + jc * D_ + dq * 8);
    const float4 r1 = *reinterpret_cast<const float4*>(rb + jc * D_ + dq * 8 + 4);
    #pragma unroll
    for (int hh = 0; hh < H_; ++hh) {
      const float4 q0 = *reinterpret_cast<const float4*>(qb + hh * HS + jc * D_ + dq * 8);
      const float4 q1 = *reinterpret_cast<const float4*>(qb + hh * HS + jc * D_ + dq * 8 + 4);
      const float4 k0 = *reinterpret_cast<const float4*>(&ks[hh * D_ + dq * 8]);
      const float4 k1 = *reinterpret_cast<const float4*>(&ks[hh * D_ + dq * 8 + 4]);
      float s = q0.x * k0.x * r0.x;
      s = fmaf(q0.y * k0.y, r0.y, s);
      s = fmaf(q0.z * k0.z, r0.z, s);
      s = fmaf(q0.w * k0.w, r0.w, s);
      s = fmaf(q1.x * k1.x, r1.x, s);
      s = fmaf(q1.y * k1.y, r1.y, s);
      s = fmaf(q1.z * k1.z, r1.z, s);
      s = fmaf(q1.w * k1.w, r1.w, s);
      s = red4(s);
      if (dq == 0 && j < station) p_smem[hh * S_ + j] = s;
    }
  }
  // diagonal cell j == i when i >= station (wave 0, lanes 0..3 = one quad)
  if (w == 0 && j4 == 0 && i >= station) {
    const float4 r0 = *reinterpret_cast<const float4*>(rb + i * D_ + dq * 8);
    const float4 r1 = *reinterpret_cast<const float4*>(rb + i * D_ + dq * 8 + 4);
    #pragma unroll
    for (int hh = 0; hh < H_; ++hh) {
      const float4 q0 = *reinterpret_cast<const float4*>(qb + hh * HS + i * D_ + dq * 8);
      const float4 q1 = *reinterpret_cast<const float4*>(qb + hh * HS + i * D_ + dq * 8 + 4);
      const float4 k0 = *reinterpret_cast<const float4*>(&ks[hh * D_ + dq * 8]);
      const float4 k1 = *reinterpret_cast<const float4*>(&ks[hh * D_ + dq * 8 + 4]);
      float s = q0.x * k0.x * r0.x;
      s = fmaf(q0.y * k0.y, r0.y, s);
      s = fmaf(q0.z * k0.z, r0.z, s);
      s = fmaf(q0.w * k0.w, r0.w, s);
      s = fmaf(q1.x * k1.x, r1.x, s);
      s = fmaf(q1.y * k1.y, r1.y, s);
      s = fmaf(q1.z * k1.z, r1.z, s);
      s = fmaf(q1.w * k1.w, r1.w, s);
      s = red4(s);
      if (dq == 0) p_smem[hh * S_ + i] = s;
    }
  }
  __syncthreads();

  // ---- softmax: wave w handles head row w (NW == H_ == 8) ----
  const bool dx = (i >= station);
  {
    const int r = w;
    float m = -1e30f;
    for (int jj = lane; jj < station; jj += 64) m = fmaxf(m, p_smem[r * S_ + jj]);
    const float dv = dx ? p_smem[r * S_ + i] : -1e30f;
    m = fmaxf(m, dv);
    #pragma unroll
    for (int o = 32; o; o >>= 1) m = fmaxf(m, __shfl_xor(m, o, 64));
    float sum = 0.f;
    for (int jj = lane; jj < station; jj += 64) {
      const float e = __expf(p_smem[r * S_ + jj] - m);
      p_smem[r * S_ + jj] = e;
      sum += e;
    }
    #pragma unroll
    for (int o = 32; o; o >>= 1) sum += __shfl_xor(sum, o, 64);
    if (dx) {
      const float e = __expf(dv - m);
      sum += e;
      if (lane == 0) p_smem[r * S_ + i] = e;
    }
    if (lane == 0) sums[r] = sum;
  }
  __syncthreads();

  // ---- attn @ V: wave w owns head w; thread (j8,dc) does its j-slice ----
  // acc is ONE float4 (4 VGPRs) -- this is the R2 spill fix.
  float4 acc = make_float4(0.f, 0.f, 0.f, 0.f);
  {
    const float* vh = vb + w * HS;
    const float* ph = p_smem + w * S_;
    #pragma unroll 4
    for (int jb = 0; jb < station; jb += 8) {
      const int j  = jb + j8;
      const int jc = j < S_ ? j : S_ - 1;
      const float4 v4 = *reinterpret_cast<const float4*>(vh + jc * D_ + dc * 4);
      float pv = 0.f;
      if (j < station) pv = ph[j];
      acc.x = fmaf(pv, v4.x, acc.x);
      acc.y = fmaf(pv, v4.y, acc.y);
      acc.z = fmaf(pv, v4.z, acc.z);
      acc.w = fmaf(pv, v4.w, acc.w);
    }
  }
  // reduce over j8 groups (lane bits 3..5); every lane ends with the full sum
  #pragma unroll
  for (int o = 8; o <= 32; o <<= 1) {
    acc.x += __shfl_xor(acc.x, o, 64);
    acc.y += __shfl_xor(acc.y, o, 64);
    acc.z += __shfl_xor(acc.z, o, 64);
    acc.w += __shfl_xor(acc.w, o, 64);
  }
  if (j8 == 0) {
    // diagonal contribution (exactly once, post-reduction)
    if (dx) {
      const float pv = p_smem[w * S_ + i];
      const float4 v4 = *reinterpret_cast<const float4*>(vb + w * HS + i * D_ + dc * 4);
      acc.x = fmaf(pv, v4.x, acc.x);
      acc.y = fmaf(pv, v4.y, acc.y);
      acc.z = fmaf(pv, v4.z, acc.z);
      acc.w = fmaf(pv, v4.w, acc.w);
    }
    const float inv = 1.f / sums[w];
    orow[w * D_ + dc * 4 + 0] = acc.x * inv;
    orow[w * D_ + dc * 4 + 1] = acc.y * inv;
    orow[w * D_ + dc * 4 + 2] = acc.z * inv;
    orow[w * D_ + dc * 4 + 3] = acc.w * inv;
  }
  __syncthreads();

  // ---- fc (thread per output column m=tid, first 4 waves) + residual + LN --
  float fca = 0.f;
  if (tid < DM_) {
    const float* wp = fc_w + tid;
    #pragma unroll 8
    for (int n4 = 0; n4 < HD_ / 4; ++n4) {
      const float4 ov = reinterpret_cast<const float4*>(orow)[n4];
      fca = fmaf(ov.x, wp[(4 * n4 + 0) * DM_], fca);
      fca = fmaf(ov.y, wp[(4 * n4 + 1) * DM_], fca);
      fca = fmaf(ov.z, wp[(4 * n4 + 2) * DM_], fca);
      fca = fmaf(ov.w, wp[(4 * n4 + 3) * DM_], fca);
    }
    fca += fc_b[tid] + hid[(size_t)n * DM_ + tid];
    float s = fca;
    #pragma unroll
    for (int o = 32; o; o >>= 1) s += __shfl_xor(s, o, 64);
    if (lane == 0) redm[w] = s;
  }
  __syncthreads();
  const float mu = (redm[0] + redm[1] + redm[2] + redm[3]) * (1.f / DM_);
  const float dd = fca - mu;
  if (tid < DM_) {
    float s = dd * dd;
    #pragma unroll
    for (int o = 32; o; o >>= 1) s += __shfl_xor(s, o, 64);
    if (lane == 0) redvr[w] = s;
  }
  __syncthreads();
  if (tid < DM_) {
    const float var = (redvr[0] + redvr[1] + redvr[2] + redvr[3]) * (1.f / DM_);
    out[(size_t)n * DM_ + tid] = dd * rsqrtf(var + 1e-6f) * ln_w[tid] + ln_b[tid];
  }
}

// ---------------------------------------------------------------------------
extern "C" void kernel_launch(void* const* d_in, const int* in_sizes, int n_in,
                              void* d_out, int out_size, void* d_ws, size_t ws_size,
                              hipStream_t stream) {
  const float* hid = (const float*)d_in[0];
  const float* rpe = (const float*)d_in[1];
  const float* wq  = (const float*)d_in[2];
  const float* wk  = (const float*)d_in[3];
  const float* wv  = (const float*)d_in[4];
  const float* fcw = (const float*)d_in[5];
  const float* fcb = (const float*)d_in[6];
  const float* lnw = (const float*)d_in[7];
  const float* lnb = (const float*)d_in[8];
  const int* station = (const int*)d_in[9];
  float* out = (float*)d_out;

  const size_t per = (size_t)B_ * H_ * S_ * D_;   // 262144 floats
  float* q_ws = (float*)d_ws;
  float* k_ws = q_ws + per;
  float* v_ws = k_ws + per;

  dim3 gA(B_ * S_ / NROW, 3);
  qkv_kernel<<<gA, 256, 0, stream>>>(hid, wq, wk, wv, q_ws, k_ws, v_ws);
  attn_fused_kernel<<<B_ * S_, 512, 0, stream>>>(
      rpe, q_ws, k_ws, v_ws, station, fcw, fcb, hid, lnw, lnb, out);
}

// Round 4
// 196.676 us; speedup vs baseline: 1.6434x; 1.3823x over previous
//
#include <hip/hip_runtime.h>
#include <hip/hip_bf16.h>

#define B_  2
#define S_  512
#define H_  8
#define D_  32
#define DM_ 256
#define HD_ 256
#define NROW 4
#define NW  8          // waves per attention block (512 threads)

// ---------------------------------------------------------------------------
// Kernel A: QKV projection.  grid = (B*S/NROW, 3), block = 256.
// out layout: (b, h, s, d).  q is pre-scaled by 1/sqrt(D).
// ---------------------------------------------------------------------------
__global__ __launch_bounds__(256) void qkv_kernel(
    const float* __restrict__ hid, const float* __restrict__ wq,
    const float* __restrict__ wk, const float* __restrict__ wv,
    float* __restrict__ qo, float* __restrict__ ko, float* __restrict__ vo)
{
  __shared__ __align__(16) float hs[NROW][DM_];
  const int r0 = blockIdx.x * NROW;                 // global row in [0, B*S)
  const float* w   = (blockIdx.y == 0) ? wq : (blockIdx.y == 1) ? wk : wv;
  float*       out = (blockIdx.y == 0) ? qo : (blockIdx.y == 1) ? ko : vo;
  const float mulf = (blockIdx.y == 0) ? 0.17677669529663687f : 1.0f;
  const int tid = threadIdx.x;

  for (int idx = tid; idx < NROW * DM_; idx += 256)
    hs[idx >> 8][idx & 255] = hid[r0 * DM_ + idx];
  __syncthreads();

  float acc[NROW] = {0.f, 0.f, 0.f, 0.f};
  const float* wp = w + tid;                        // column m = tid
  #pragma unroll 8
  for (int c4 = 0; c4 < DM_ / 4; ++c4) {
    const float w0 = wp[(4 * c4 + 0) * HD_];
    const float w1 = wp[(4 * c4 + 1) * HD_];
    const float w2 = wp[(4 * c4 + 2) * HD_];
    const float w3 = wp[(4 * c4 + 3) * HD_];
    #pragma unroll
    for (int r = 0; r < NROW; ++r) {
      const float4 hv = reinterpret_cast<const float4*>(&hs[r][0])[c4];
      acc[r] = fmaf(hv.x, w0, acc[r]);
      acc[r] = fmaf(hv.y, w1, acc[r]);
      acc[r] = fmaf(hv.z, w2, acc[r]);
      acc[r] = fmaf(hv.w, w3, acc[r]);
    }
  }
  const int h = tid >> 5, d = tid & 31;
  #pragma unroll
  for (int r = 0; r < NROW; ++r) {
    const int g = r0 + r;
    const int b = g >> 9, s = g & (S_ - 1);
    out[((b * H_ + h) * S_ + s) * D_ + d] = acc[r] * mulf;
  }
}

// 4-lane (quad) butterfly sum via DPP: all 4 lanes of the quad get the sum.
__device__ __forceinline__ float red4(float x) {
  int i;
  i = __builtin_amdgcn_mov_dpp(__float_as_int(x), 0xB1, 0xf, 0xf, true); // quad_perm xor1
  x += __int_as_float(i);
  i = __builtin_amdgcn_mov_dpp(__float_as_int(x), 0x4E, 0xf, 0xf, true); // quad_perm xor2
  x += __int_as_float(i);
  return x;
}

// ---------------------------------------------------------------------------
// Kernel B (fused): scores + mask + softmax + attn@V + fc + residual + LN.
// One block per (b, i): grid = B*S = 1024, block = 512 (8 waves).
// R3 post-mortem: the SCORE loop's 8-head unroll held 16 q-float4 live
// (~100 VGPR demand) against the 64-reg cap -> allocator spilled (180 MB
// scratch traffic).  R4 changes the decomposition, not the cap: WAVE w
// OWNS HEAD w in every phase.  Per-wave live state = own K frag (2 float4)
// + per-j transients (4 float4) ~= 50 VGPR, genuinely under the cap.
// Cost: rpe row read by 8 waves instead of 1 (8x L2 traffic, ~7 us at L2
// BW) -- cheap; we're buying occupancy (32 waves/CU) for latency hiding,
// which R1 showed is the limiter (VALUBusy 25%, all BW <40%).
// Score mapping: lane=(j4,dq), 4 dq-lanes cover one j's 128B d-row (32B each).
// attn@V mapping: lane=(j8,dc).
// scores[h,j] = sum_d q'[h,j,d] k[h,i,d] rpe[i,j,d]  (q' pre-scaled);
// mask: j < station OR j == i.
// NOTE: register arrays use compile-time indices ONLY (dynamic index ->
// scratch demotion -> spill traffic).
// ---------------------------------------------------------------------------
__global__ __launch_bounds__(512, 8) void attn_fused_kernel(
    const float* __restrict__ rpe, const float* __restrict__ q_ws,
    const float* __restrict__ k_ws, const float* __restrict__ v_ws,
    const int* __restrict__ station_p, const float* __restrict__ fc_w,
    const float* __restrict__ fc_b, const float* __restrict__ hid,
    const float* __restrict__ ln_w, const float* __restrict__ ln_b,
    float* __restrict__ out)
{
  __shared__ __align__(16) float p_smem[H_ * S_];   // 16 KB
  __shared__ __align__(16) float ks[H_ * D_];       // 1 KB K row, 8 heads
  __shared__ __align__(16) float orow[HD_];         // 1 KB attention output row
  __shared__ float sums[H_];
  __shared__ float redm[4];
  __shared__ float redvr[4];

  const int tid  = threadIdx.x;
  const int w    = tid >> 6, lane = tid & 63;
  const int j4   = lane >> 2, dq = lane & 3;        // score mapping
  const int j8   = lane >> 3, dc = lane & 7;        // attn@V mapping
  const int n    = blockIdx.x;                      // 0..1023
  const int b    = n >> 9;
  const int i    = n & (S_ - 1);
  const int HS   = S_ * D_;                         // head stride

  int station = station_p[0];
  station = station > S_ ? S_ : (station < 0 ? 0 : station);
  const bool dx = (i >= station);

  const float* qb = q_ws + (size_t)(b * H_) * S_ * D_;
  const float* kb = k_ws + (size_t)(b * H_) * S_ * D_;
  const float* vb = v_ws + (size_t)(b * H_) * S_ * D_;
  const float* rb = rpe + ((size_t)b * S_ + i) * S_ * D_;

  // stage K row i for all 8 heads into LDS
  if (tid < H_ * D_) {
    const int h = tid >> 5, d = tid & 31;
    ks[tid] = kb[h * HS + i * D_ + d];
  }
  __syncthreads();

  // ---- scores: wave w owns head w; lanes (j4,dq) cover 16 j per pass ----
  {
    // loop-invariant K fragment for this wave's head (8 VGPRs)
    const float4 k0 = *reinterpret_cast<const float4*>(&ks[w * D_ + dq * 8]);
    const float4 k1 = *reinterpret_cast<const float4*>(&ks[w * D_ + dq * 8 + 4]);
    const float* qh = qb + w * HS;
    float* ph = p_smem + w * S_;

    #pragma unroll 2
    for (int jb = 0; jb < station; jb += 16) {
      const int j = jb + j4;                        // j < S_ always (station<=S_)
      const float4 r0 = *reinterpret_cast<const float4*>(rb + j * D_ + dq * 8);
      const float4 r1 = *reinterpret_cast<const float4*>(rb + j * D_ + dq * 8 + 4);
      const float4 q0 = *reinterpret_cast<const float4*>(qh + j * D_ + dq * 8);
      const float4 q1 = *reinterpret_cast<const float4*>(qh + j * D_ + dq * 8 + 4);
      float s = q0.x * k0.x * r0.x;
      s = fmaf(q0.y * k0.y, r0.y, s);
      s = fmaf(q0.z * k0.z, r0.z, s);
      s = fmaf(q0.w * k0.w, r0.w, s);
      s = fmaf(q1.x * k1.x, r1.x, s);
      s = fmaf(q1.y * k1.y, r1.y, s);
      s = fmaf(q1.z * k1.z, r1.z, s);
      s = fmaf(q1.w * k1.w, r1.w, s);
      s = red4(s);
      if (dq == 0 && j < station) ph[j] = s;
    }
    // diagonal cell j == i when i >= station (lanes 0..3 = one quad)
    if (j4 == 0 && dx) {
      const float4 r0 = *reinterpret_cast<const float4*>(rb + i * D_ + dq * 8);
      const float4 r1 = *reinterpret_cast<const float4*>(rb + i * D_ + dq * 8 + 4);
      const float4 q0 = *reinterpret_cast<const float4*>(qh + i * D_ + dq * 8);
      const float4 q1 = *reinterpret_cast<const float4*>(qh + i * D_ + dq * 8 + 4);
      float s = q0.x * k0.x * r0.x;
      s = fmaf(q0.y * k0.y, r0.y, s);
      s = fmaf(q0.z * k0.z, r0.z, s);
      s = fmaf(q0.w * k0.w, r0.w, s);
      s = fmaf(q1.x * k1.x, r1.x, s);
      s = fmaf(q1.y * k1.y, r1.y, s);
      s = fmaf(q1.z * k1.z, r1.z, s);
      s = fmaf(q1.w * k1.w, r1.w, s);
      s = red4(s);
      if (dq == 0) ph[i] = s;
    }
  }
  __syncthreads();

  // ---- softmax: wave w handles head row w (NW == H_ == 8) ----
  {
    const int r = w;
    float m = -1e30f;
    for (int jj = lane; jj < station; jj += 64) m = fmaxf(m, p_smem[r * S_ + jj]);
    const float dv = dx ? p_smem[r * S_ + i] : -1e30f;
    m = fmaxf(m, dv);
    #pragma unroll
    for (int o = 32; o; o >>= 1) m = fmaxf(m, __shfl_xor(m, o, 64));
    float sum = 0.f;
    for (int jj = lane; jj < station; jj += 64) {
      const float e = __expf(p_smem[r * S_ + jj] - m);
      p_smem[r * S_ + jj] = e;
      sum += e;
    }
    #pragma unroll
    for (int o = 32; o; o >>= 1) sum += __shfl_xor(sum, o, 64);
    if (dx) {
      const float e = __expf(dv - m);
      sum += e;
      if (lane == 0) p_smem[r * S_ + i] = e;
    }
    if (lane == 0) sums[r] = sum;
  }
  __syncthreads();

  // ---- attn @ V: wave w owns head w; thread (j8,dc) does its j-slice ----
  float4 acc = make_float4(0.f, 0.f, 0.f, 0.f);
  {
    const float* vh = vb + w * HS;
    const float* ph = p_smem + w * S_;
    #pragma unroll 4
    for (int jb = 0; jb < station; jb += 8) {
      const int j  = jb + j8;
      const int jc = j < S_ ? j : S_ - 1;
      const float4 v4 = *reinterpret_cast<const float4*>(vh + jc * D_ + dc * 4);
      float pv = 0.f;
      if (j < station) pv = ph[j];
      acc.x = fmaf(pv, v4.x, acc.x);
      acc.y = fmaf(pv, v4.y, acc.y);
      acc.z = fmaf(pv, v4.z, acc.z);
      acc.w = fmaf(pv, v4.w, acc.w);
    }
  }
  // reduce over j8 groups (lane bits 3..5); every lane ends with the full sum
  #pragma unroll
  for (int o = 8; o <= 32; o <<= 1) {
    acc.x += __shfl_xor(acc.x, o, 64);
    acc.y += __shfl_xor(acc.y, o, 64);
    acc.z += __shfl_xor(acc.z, o, 64);
    acc.w += __shfl_xor(acc.w, o, 64);
  }
  if (j8 == 0) {
    // diagonal contribution (exactly once, post-reduction)
    if (dx) {
      const float pv = p_smem[w * S_ + i];
      const float4 v4 = *reinterpret_cast<const float4*>(vb + w * HS + i * D_ + dc * 4);
      acc.x = fmaf(pv, v4.x, acc.x);
      acc.y = fmaf(pv, v4.y, acc.y);
      acc.z = fmaf(pv, v4.z, acc.z);
      acc.w = fmaf(pv, v4.w, acc.w);
    }
    const float inv = 1.f / sums[w];
    orow[w * D_ + dc * 4 + 0] = acc.x * inv;
    orow[w * D_ + dc * 4 + 1] = acc.y * inv;
    orow[w * D_ + dc * 4 + 2] = acc.z * inv;
    orow[w * D_ + dc * 4 + 3] = acc.w * inv;
  }
  __syncthreads();

  // ---- fc (thread per output column m=tid, first 4 waves) + residual + LN --
  float fca = 0.f;
  if (tid < DM_) {
    const float* wp = fc_w + tid;
    #pragma unroll 8
    for (int n4 = 0; n4 < HD_ / 4; ++n4) {
      const float4 ov = reinterpret_cast<const float4*>(orow)[n4];
      fca = fmaf(ov.x, wp[(4 * n4 + 0) * DM_], fca);
      fca = fmaf(ov.y, wp[(4 * n4 + 1) * DM_], fca);
      fca = fmaf(ov.z, wp[(4 * n4 + 2) * DM_], fca);
      fca = fmaf(ov.w, wp[(4 * n4 + 3) * DM_], fca);
    }
    fca += fc_b[tid] + hid[(size_t)n * DM_ + tid];
    float s = fca;
    #pragma unroll
    for (int o = 32; o; o >>= 1) s += __shfl_xor(s, o, 64);
    if (lane == 0) redm[w] = s;
  }
  __syncthreads();
  const float mu = (redm[0] + redm[1] + redm[2] + redm[3]) * (1.f / DM_);
  const float dd = fca - mu;
  if (tid < DM_) {
    float s = dd * dd;
    #pragma unroll
    for (int o = 32; o; o >>= 1) s += __shfl_xor(s, o, 64);
    if (lane == 0) redvr[w] = s;
  }
  __syncthreads();
  if (tid < DM_) {
    const float var = (redvr[0] + redvr[1] + redvr[2] + redvr[3]) * (1.f / DM_);
    out[(size_t)n * DM_ + tid] = dd * rsqrtf(var + 1e-6f) * ln_w[tid] + ln_b[tid];
  }
}

// ---------------------------------------------------------------------------
extern "C" void kernel_launch(void* const* d_in, const int* in_sizes, int n_in,
                              void* d_out, int out_size, void* d_ws, size_t ws_size,
                              hipStream_t stream) {
  const float* hid = (const float*)d_in[0];
  const float* rpe = (const float*)d_in[1];
  const float* wq  = (const float*)d_in[2];
  const float* wk  = (const float*)d_in[3];
  const float* wv  = (const float*)d_in[4];
  const float* fcw = (const float*)d_in[5];
  const float* fcb = (const float*)d_in[6];
  const float* lnw = (const float*)d_in[7];
  const float* lnb = (const float*)d_in[8];
  const int* station = (const int*)d_in[9];
  float* out = (float*)d_out;

  const size_t per = (size_t)B_ * H_ * S_ * D_;   // 262144 floats
  float* q_ws = (float*)d_ws;
  float* k_ws = q_ws + per;
  float* v_ws = k_ws + per;

  dim3 gA(B_ * S_ / NROW, 3);
  qkv_kernel<<<gA, 256, 0, stream>>>(hid, wq, wk, wv, q_ws, k_ws, v_ws);
  attn_fused_kernel<<<B_ * S_, 512, 0, stream>>>(
      rpe, q_ws, k_ws, v_ws, station, fcw, fcb, hid, lnw, lnb, out);
}

// Round 5
// 153.664 us; speedup vs baseline: 2.1034x; 1.2799x over previous
//
#include <hip/hip_runtime.h>
#include <hip/hip_bf16.h>

#define B_  2
#define S_  512
#define H_  8
#define D_  32
#define DM_ 256
#define HD_ 256
#define NROW 4
#define NW  8          // waves per attention block (512 threads)
#define RSTAGE 256     // rpe rows staged in LDS (32 KB); j >= RSTAGE -> global

// ---------------------------------------------------------------------------
// Kernel A: QKV projection.  grid = (B*S/NROW, 3), block = 256.
// out layout: (b, h, s, d).  q is pre-scaled by 1/sqrt(D).
// ---------------------------------------------------------------------------
__global__ __launch_bounds__(256) void qkv_kernel(
    const float* __restrict__ hid, const float* __restrict__ wq,
    const float* __restrict__ wk, const float* __restrict__ wv,
    float* __restrict__ qo, float* __restrict__ ko, float* __restrict__ vo)
{
  __shared__ __align__(16) float hs[NROW][DM_];
  const int r0 = blockIdx.x * NROW;                 // global row in [0, B*S)
  const float* w   = (blockIdx.y == 0) ? wq : (blockIdx.y == 1) ? wk : wv;
  float*       out = (blockIdx.y == 0) ? qo : (blockIdx.y == 1) ? ko : vo;
  const float mulf = (blockIdx.y == 0) ? 0.17677669529663687f : 1.0f;
  const int tid = threadIdx.x;

  for (int idx = tid; idx < NROW * DM_; idx += 256)
    hs[idx >> 8][idx & 255] = hid[r0 * DM_ + idx];
  __syncthreads();

  float acc[NROW] = {0.f, 0.f, 0.f, 0.f};
  const float* wp = w + tid;                        // column m = tid
  #pragma unroll 8
  for (int c4 = 0; c4 < DM_ / 4; ++c4) {
    const float w0 = wp[(4 * c4 + 0) * HD_];
    const float w1 = wp[(4 * c4 + 1) * HD_];
    const float w2 = wp[(4 * c4 + 2) * HD_];
    const float w3 = wp[(4 * c4 + 3) * HD_];
    #pragma unroll
    for (int r = 0; r < NROW; ++r) {
      const float4 hv = reinterpret_cast<const float4*>(&hs[r][0])[c4];
      acc[r] = fmaf(hv.x, w0, acc[r]);
      acc[r] = fmaf(hv.y, w1, acc[r]);
      acc[r] = fmaf(hv.z, w2, acc[r]);
      acc[r] = fmaf(hv.w, w3, acc[r]);
    }
  }
  const int h = tid >> 5, d = tid & 31;
  #pragma unroll
  for (int r = 0; r < NROW; ++r) {
    const int g = r0 + r;
    const int b = g >> 9, s = g & (S_ - 1);
    out[((b * H_ + h) * S_ + s) * D_ + d] = acc[r] * mulf;
  }
}

// 4-lane (quad) butterfly sum via DPP: all 4 lanes of the quad get the sum.
__device__ __forceinline__ float red4(float x) {
  int i;
  i = __builtin_amdgcn_mov_dpp(__float_as_int(x), 0xB1, 0xf, 0xf, true); // quad_perm xor1
  x += __int_as_float(i);
  i = __builtin_amdgcn_mov_dpp(__float_as_int(x), 0x4E, 0xf, 0xf, true); // quad_perm xor2
  x += __int_as_float(i);
  return x;
}

// ---------------------------------------------------------------------------
// Kernel B (fused): scores + mask + softmax + attn@V + fc + residual + LN.
// One block per (b, i): grid = B*S = 1024, block = 512 (8 waves).
// R4 post-mortem: (512,8) squeezed VGPR to 24 -> ONE outstanding load per
// wave (ILP collapse) while each of 8 waves re-read the whole rpe row (8x
// load duplication) -> 95 us despite 87% occupancy.  R5 fixes all three
// terms of time ~ loads / (waves * in_flight):
//  (1) rpe row staged ONCE per block into LDS (32 KB, XOR-swizzled --
//      a row is exactly 128 B = 32 banks, so unswizzled column reads are
//      16-way conflicts).  Score loop's global loads: 4/pass -> 2/pass.
//  (2) cap relaxed to (512,6) = 85 VGPR: unroll-2 score loop (~60-70 live)
//      keeps 4 q-loads + 4 LDS reads in flight -- no squeeze, no spill.
//  (3) LDS 50.4 KB -> 3 blocks/CU -> 24 waves/CU, matching 6 waves/SIMD.
// Wave w owns head w in every phase.  station > RSTAGE falls back to a
// global-read loop (empty for this input); diag reads rpe from global.
// Score mapping: lane=(j4,dq), 4 dq-lanes cover one j's 128B d-row.
// attn@V mapping: lane=(j8,dc).
// scores[h,j] = sum_d q'[h,j,d] k[h,i,d] rpe[i,j,d]  (q' pre-scaled);
// mask: j < station OR j == i.
// ---------------------------------------------------------------------------
#define RSL(j, c) (((j) << 3) | ((c) ^ ((j) & 7)))   // swizzled float4 slot

__global__ __launch_bounds__(512, 6) void attn_fused_kernel(
    const float* __restrict__ rpe, const float* __restrict__ q_ws,
    const float* __restrict__ k_ws, const float* __restrict__ v_ws,
    const int* __restrict__ station_p, const float* __restrict__ fc_w,
    const float* __restrict__ fc_b, const float* __restrict__ hid,
    const float* __restrict__ ln_w, const float* __restrict__ ln_b,
    float* __restrict__ out)
{
  __shared__ __align__(16) float p_smem[H_ * S_];      // 16 KB
  __shared__ __align__(16) float rpe_s[RSTAGE * D_];   // 32 KB, swizzled
  __shared__ __align__(16) float ks[H_ * D_];          // 1 KB K row, 8 heads
  __shared__ __align__(16) float orow[HD_];            // 1 KB attn output row
  __shared__ float sums[H_];
  __shared__ float redm[4];
  __shared__ float redvr[4];

  const int tid  = threadIdx.x;
  const int w    = tid >> 6, lane = tid & 63;
  const int j4   = lane >> 2, dq = lane & 3;        // score mapping
  const int j8   = lane >> 3, dc = lane & 7;        // attn@V mapping
  const int n    = blockIdx.x;                      // 0..1023
  const int b    = n >> 9;
  const int i    = n & (S_ - 1);
  const int HS   = S_ * D_;                         // head stride

  int station = station_p[0];
  station = station > S_ ? S_ : (station < 0 ? 0 : station);
  const bool dx = (i >= station);
  const int nstage = station < RSTAGE ? station : RSTAGE;

  const float* qb = q_ws + (size_t)(b * H_) * S_ * D_;
  const float* kb = k_ws + (size_t)(b * H_) * S_ * D_;
  const float* vb = v_ws + (size_t)(b * H_) * S_ * D_;
  const float* rb = rpe + ((size_t)b * S_ + i) * S_ * D_;

  // stage K row i (all 8 heads) and the rpe row (swizzled) into LDS
  if (tid < H_ * D_) {
    const int h = tid >> 5, d = tid & 31;
    ks[tid] = kb[h * HS + i * D_ + d];
  }
  {
    float4* rs4 = reinterpret_cast<float4*>(rpe_s);
    const float4* rb4 = reinterpret_cast<const float4*>(rb);
    for (int g = tid; g < nstage * 8; g += 512) {
      const int j = g >> 3, c = g & 7;
      rs4[RSL(j, c)] = rb4[g];
    }
  }
  __syncthreads();

  // ---- scores: wave w owns head w; lanes (j4,dq) cover 16 j per pass ----
  {
    const float4 k0 = *reinterpret_cast<const float4*>(&ks[w * D_ + dq * 8]);
    const float4 k1 = *reinterpret_cast<const float4*>(&ks[w * D_ + dq * 8 + 4]);
    const float* qh = qb + w * HS;
    float* ph = p_smem + w * S_;
    const float4* rs4 = reinterpret_cast<const float4*>(rpe_s);

    // LDS-staged j range
    #pragma unroll 2
    for (int jb = 0; jb < nstage; jb += 16) {
      const int j = jb + j4;                        // j <= 511 always
      const float4 q0 = *reinterpret_cast<const float4*>(qh + j * D_ + dq * 8);
      const float4 q1 = *reinterpret_cast<const float4*>(qh + j * D_ + dq * 8 + 4);
      const float4 r0 = rs4[RSL(j, 2 * dq)];
      const float4 r1 = rs4[RSL(j, 2 * dq + 1)];
      float s = q0.x * k0.x * r0.x;
      s = fmaf(q0.y * k0.y, r0.y, s);
      s = fmaf(q0.z * k0.z, r0.z, s);
      s = fmaf(q0.w * k0.w, r0.w, s);
      s = fmaf(q1.x * k1.x, r1.x, s);
      s = fmaf(q1.y * k1.y, r1.y, s);
      s = fmaf(q1.z * k1.z, r1.z, s);
      s = fmaf(q1.w * k1.w, r1.w, s);
      s = red4(s);
      if (dq == 0 && j < station) ph[j] = s;
    }
    // global fallback j range (station > RSTAGE only)
    #pragma unroll 2
    for (int jb = RSTAGE; jb < station; jb += 16) {
      const int j = jb + j4;
      const float4 q0 = *reinterpret_cast<const float4*>(qh + j * D_ + dq * 8);
      const float4 q1 = *reinterpret_cast<const float4*>(qh + j * D_ + dq * 8 + 4);
      const float4 r0 = *reinterpret_cast<const float4*>(rb + j * D_ + dq * 8);
      const float4 r1 = *reinterpret_cast<const float4*>(rb + j * D_ + dq * 8 + 4);
      float s = q0.x * k0.x * r0.x;
      s = fmaf(q0.y * k0.y, r0.y, s);
      s = fmaf(q0.z * k0.z, r0.z, s);
      s = fmaf(q0.w * k0.w, r0.w, s);
      s = fmaf(q1.x * k1.x, r1.x, s);
      s = fmaf(q1.y * k1.y, r1.y, s);
      s = fmaf(q1.z * k1.z, r1.z, s);
      s = fmaf(q1.w * k1.w, r1.w, s);
      s = red4(s);
      if (dq == 0 && j < station) ph[j] = s;
    }
    // diagonal cell j == i when i >= station (lanes 0..3; rpe from global)
    if (j4 == 0 && dx) {
      const float4 r0 = *reinterpret_cast<const float4*>(rb + i * D_ + dq * 8);
      const float4 r1 = *reinterpret_cast<const float4*>(rb + i * D_ + dq * 8 + 4);
      const float4 q0 = *reinterpret_cast<const float4*>(qh + i * D_ + dq * 8);
      const float4 q1 = *reinterpret_cast<const float4*>(qh + i * D_ + dq * 8 + 4);
      float s = q0.x * k0.x * r0.x;
      s = fmaf(q0.y * k0.y, r0.y, s);
      s = fmaf(q0.z * k0.z, r0.z, s);
      s = fmaf(q0.w * k0.w, r0.w, s);
      s = fmaf(q1.x * k1.x, r1.x, s);
      s = fmaf(q1.y * k1.y, r1.y, s);
      s = fmaf(q1.z * k1.z, r1.z, s);
      s = fmaf(q1.w * k1.w, r1.w, s);
      s = red4(s);
      if (dq == 0) ph[i] = s;
    }
  }
  __syncthreads();

  // ---- softmax: wave w handles head row w (NW == H_ == 8) ----
  {
    const int r = w;
    float m = -1e30f;
    for (int jj = lane; jj < station; jj += 64) m = fmaxf(m, p_smem[r * S_ + jj]);
    const float dv = dx ? p_smem[r * S_ + i] : -1e30f;
    m = fmaxf(m, dv);
    #pragma unroll
    for (int o = 32; o; o >>= 1) m = fmaxf(m, __shfl_xor(m, o, 64));
    float sum = 0.f;
    for (int jj = lane; jj < station; jj += 64) {
      const float e = __expf(p_smem[r * S_ + jj] - m);
      p_smem[r * S_ + jj] = e;
      sum += e;
    }
    #pragma unroll
    for (int o = 32; o; o >>= 1) sum += __shfl_xor(sum, o, 64);
    if (dx) {
      const float e = __expf(dv - m);
      sum += e;
      if (lane == 0) p_smem[r * S_ + i] = e;
    }
    if (lane == 0) sums[r] = sum;
  }
  __syncthreads();

  // ---- attn @ V: wave w owns head w; thread (j8,dc) does its j-slice ----
  float4 acc = make_float4(0.f, 0.f, 0.f, 0.f);
  {
    const float* vh = vb + w * HS;
    const float* ph = p_smem + w * S_;
    #pragma unroll 4
    for (int jb = 0; jb < station; jb += 8) {
      const int j  = jb + j8;
      const int jc = j < S_ ? j : S_ - 1;
      const float4 v4 = *reinterpret_cast<const float4*>(vh + jc * D_ + dc * 4);
      float pv = 0.f;
      if (j < station) pv = ph[j];
      acc.x = fmaf(pv, v4.x, acc.x);
      acc.y = fmaf(pv, v4.y, acc.y);
      acc.z = fmaf(pv, v4.z, acc.z);
      acc.w = fmaf(pv, v4.w, acc.w);
    }
  }
  // reduce over j8 groups (lane bits 3..5); every lane ends with the full sum
  #pragma unroll
  for (int o = 8; o <= 32; o <<= 1) {
    acc.x += __shfl_xor(acc.x, o, 64);
    acc.y += __shfl_xor(acc.y, o, 64);
    acc.z += __shfl_xor(acc.z, o, 64);
    acc.w += __shfl_xor(acc.w, o, 64);
  }
  if (j8 == 0) {
    // diagonal contribution (exactly once, post-reduction)
    if (dx) {
      const float pv = p_smem[w * S_ + i];
      const float4 v4 = *reinterpret_cast<const float4*>(vb + w * HS + i * D_ + dc * 4);
      acc.x = fmaf(pv, v4.x, acc.x);
      acc.y = fmaf(pv, v4.y, acc.y);
      acc.z = fmaf(pv, v4.z, acc.z);
      acc.w = fmaf(pv, v4.w, acc.w);
    }
    const float inv = 1.f / sums[w];
    orow[w * D_ + dc * 4 + 0] = acc.x * inv;
    orow[w * D_ + dc * 4 + 1] = acc.y * inv;
    orow[w * D_ + dc * 4 + 2] = acc.z * inv;
    orow[w * D_ + dc * 4 + 3] = acc.w * inv;
  }
  __syncthreads();

  // ---- fc (thread per output column m=tid, first 4 waves) + residual + LN --
  float fca = 0.f;
  if (tid < DM_) {
    const float* wp = fc_w + tid;
    #pragma unroll 8
    for (int n4 = 0; n4 < HD_ / 4; ++n4) {
      const float4 ov = reinterpret_cast<const float4*>(orow)[n4];
      fca = fmaf(ov.x, wp[(4 * n4 + 0) * DM_], fca);
      fca = fmaf(ov.y, wp[(4 * n4 + 1) * DM_], fca);
      fca = fmaf(ov.z, wp[(4 * n4 + 2) * DM_], fca);
      fca = fmaf(ov.w, wp[(4 * n4 + 3) * DM_], fca);
    }
    fca += fc_b[tid] + hid[(size_t)n * DM_ + tid];
    float s = fca;
    #pragma unroll
    for (int o = 32; o; o >>= 1) s += __shfl_xor(s, o, 64);
    if (lane == 0) redm[w] = s;
  }
  __syncthreads();
  const float mu = (redm[0] + redm[1] + redm[2] + redm[3]) * (1.f / DM_);
  const float dd = fca - mu;
  if (tid < DM_) {
    float s = dd * dd;
    #pragma unroll
    for (int o = 32; o; o >>= 1) s += __shfl_xor(s, o, 64);
    if (lane == 0) redvr[w] = s;
  }
  __syncthreads();
  if (tid < DM_) {
    const float var = (redvr[0] + redvr[1] + redvr[2] + redvr[3]) * (1.f / DM_);
    out[(size_t)n * DM_ + tid] = dd * rsqrtf(var + 1e-6f) * ln_w[tid] + ln_b[tid];
  }
}

// ---------------------------------------------------------------------------
extern "C" void kernel_launch(void* const* d_in, const int* in_sizes, int n_in,
                              void* d_out, int out_size, void* d_ws, size_t ws_size,
                              hipStream_t stream) {
  const float* hid = (const float*)d_in[0];
  const float* rpe = (const float*)d_in[1];
  const float* wq  = (const float*)d_in[2];
  const float* wk  = (const float*)d_in[3];
  const float* wv  = (const float*)d_in[4];
  const float* fcw = (const float*)d_in[5];
  const float* fcb = (const float*)d_in[6];
  const float* lnw = (const float*)d_in[7];
  const float* lnb = (const float*)d_in[8];
  const int* station = (const int*)d_in[9];
  float* out = (float*)d_out;

  const size_t per = (size_t)B_ * H_ * S_ * D_;   // 262144 floats
  float* q_ws = (float*)d_ws;
  float* k_ws = q_ws + per;
  float* v_ws = k_ws + per;

  dim3 gA(B_ * S_ / NROW, 3);
  qkv_kernel<<<gA, 256, 0, stream>>>(hid, wq, wk, wv, q_ws, k_ws, v_ws);
  attn_fused_kernel<<<B_ * S_, 512, 0, stream>>>(
      rpe, q_ws, k_ws, v_ws, station, fcw, fcb, hid, lnw, lnb, out);
}

// Round 6
// 148.870 us; speedup vs baseline: 2.1711x; 1.0322x over previous
//
#include <hip/hip_runtime.h>
#include <hip/hip_bf16.h>

#define B_  2
#define S_  512
#define H_  8
#define D_  32
#define DM_ 256
#define HD_ 256
#define NROW 8         // rows per qkv block
#define TI  2          // i-rows per attention block
#define CH  64         // rpe chunk rows staged per buffer

// ---------------------------------------------------------------------------
// Kernel A: QKV projection.  grid = (B*S/NROW, 3), block = 256.
// out layout: (b, h, s, d).  q is pre-scaled by 1/sqrt(D).
// NROW=8 halves weight L2 traffic vs NROW=4 (192 -> 96 MB aggregate).
// ---------------------------------------------------------------------------
__global__ __launch_bounds__(256) void qkv_kernel(
    const float* __restrict__ hid, const float* __restrict__ wq,
    const float* __restrict__ wk, const float* __restrict__ wv,
    float* __restrict__ qo, float* __restrict__ ko, float* __restrict__ vo)
{
  __shared__ __align__(16) float hs[NROW][DM_];
  const int r0 = blockIdx.x * NROW;                 // global row in [0, B*S)
  const float* w   = (blockIdx.y == 0) ? wq : (blockIdx.y == 1) ? wk : wv;
  float*       out = (blockIdx.y == 0) ? qo : (blockIdx.y == 1) ? ko : vo;
  const float mulf = (blockIdx.y == 0) ? 0.17677669529663687f : 1.0f;
  const int tid = threadIdx.x;

  for (int idx = tid; idx < NROW * DM_; idx += 256)
    hs[idx >> 8][idx & 255] = hid[r0 * DM_ + idx];
  __syncthreads();

  float acc[NROW] = {0.f, 0.f, 0.f, 0.f, 0.f, 0.f, 0.f, 0.f};
  const float* wp = w + tid;                        // column m = tid
  #pragma unroll 4
  for (int c4 = 0; c4 < DM_ / 4; ++c4) {
    const float w0 = wp[(4 * c4 + 0) * HD_];
    const float w1 = wp[(4 * c4 + 1) * HD_];
    const float w2 = wp[(4 * c4 + 2) * HD_];
    const float w3 = wp[(4 * c4 + 3) * HD_];
    #pragma unroll
    for (int r = 0; r < NROW; ++r) {
      const float4 hv = reinterpret_cast<const float4*>(&hs[r][0])[c4];
      acc[r] = fmaf(hv.x, w0, acc[r]);
      acc[r] = fmaf(hv.y, w1, acc[r]);
      acc[r] = fmaf(hv.z, w2, acc[r]);
      acc[r] = fmaf(hv.w, w3, acc[r]);
    }
  }
  const int h = tid >> 5, d = tid & 31;
  #pragma unroll
  for (int r = 0; r < NROW; ++r) {
    const int g = r0 + r;
    const int b = g >> 9, s = g & (S_ - 1);
    out[((b * H_ + h) * S_ + s) * D_ + d] = acc[r] * mulf;
  }
}

// 4-lane (quad) butterfly sum via DPP: all 4 lanes of the quad get the sum.
__device__ __forceinline__ float red4(float x) {
  int i;
  i = __builtin_amdgcn_mov_dpp(__float_as_int(x), 0xB1, 0xf, 0xf, true); // quad_perm xor1
  x += __int_as_float(i);
  i = __builtin_amdgcn_mov_dpp(__float_as_int(x), 0x4E, 0xf, 0xf, true); // quad_perm xor2
  x += __int_as_float(i);
  return x;
}

// swizzled float4 slot within a CH*D_ rpe chunk (jj = local row, c = 16B col)
#define RSL(jj, c) (((jj) << 3) | ((c) ^ ((jj) & 7)))

// ---------------------------------------------------------------------------
// Kernel B (fused): scores + mask + softmax + attn@V + fc + residual + LN.
// R5 post-mortem: kernel healthy (no spill, conflicts minor) but L2 bytes
// unchanged (~800 MB -> 18 TB/s sustained = effective ceiling).  R6 halves
// the bytes via TI=2 i-rows per block (grid 512, 8 waves, wave w = head w):
//   q/V/fcw amortized over 2 rows (256->128 MB each); rpe chunk-staged in
//   LDS double-buffer (CH=64 rows x 2 i x 2 bufs = 32 KB), staged ONCE per
//   block so all 8 waves share it (32 MB total, no 8x duplication, no
//   RSTAGE fallback -- works for any station <= 512).
// Register discipline (R2/R3 lesson): K frags 16 + q 8 + rpe transients 16
// -> peak ~80 under the (512,4)=128 cap.  LDS ~70 KB -> 2 blocks/CU.
// Score mapping: lane=(j4,dq), 4 dq-lanes cover one j's 128B d-row.
// attn@V mapping: lane=(j8,dc); acc0/acc1 share each V load.
// scores[ii,h,j] = sum_d q'[h,j,d] k[h,i0+ii,d] rpe[i0+ii,j,d];
// mask: j < station OR j == i.
// ---------------------------------------------------------------------------
__global__ __launch_bounds__(512, 4) void attn_fused_kernel(
    const float* __restrict__ rpe, const float* __restrict__ q_ws,
    const float* __restrict__ k_ws, const float* __restrict__ v_ws,
    const int* __restrict__ station_p, const float* __restrict__ fc_w,
    const float* __restrict__ fc_b, const float* __restrict__ hid,
    const float* __restrict__ ln_w, const float* __restrict__ ln_b,
    float* __restrict__ out)
{
  __shared__ __align__(16) float p_smem[TI][H_][S_];      // 32 KB
  __shared__ __align__(16) float rpe_s[2][TI][CH * D_];   // 32 KB, swizzled
  __shared__ __align__(16) float ks[TI][H_ * D_];         // 2 KB
  __shared__ __align__(16) float orow[TI][HD_];           // 2 KB
  __shared__ float sums[TI][H_];
  __shared__ float redm[TI][4];
  __shared__ float redvr[TI][4];

  const int tid  = threadIdx.x;
  const int w    = tid >> 6, lane = tid & 63;
  const int j4   = lane >> 2, dq = lane & 3;        // score mapping
  const int j8   = lane >> 3, dc = lane & 7;        // attn@V mapping
  const int n    = blockIdx.x;                      // 0..511
  const int b    = n >> 8;
  const int i0   = (n & 255) * TI;
  const int HS   = S_ * D_;                         // head stride

  int station = station_p[0];
  station = station > S_ ? S_ : (station < 0 ? 0 : station);
  const bool dx0 = (i0 >= station);
  const bool dx1 = (i0 + 1 >= station);

  const float* qb = q_ws + (size_t)(b * H_) * S_ * D_;
  const float* kb = k_ws + (size_t)(b * H_) * S_ * D_;
  const float* vb = v_ws + (size_t)(b * H_) * S_ * D_;
  const float* rb0 = rpe + ((size_t)(b * S_ + i0) * S_) * D_;
  const float* rb1 = rpe + ((size_t)(b * S_ + i0 + 1) * S_) * D_;

  // stage K rows i0,i0+1 (all 8 heads): exactly 512 elements = 1/thread
  {
    const int ii = tid >> 8, rest = tid & 255;
    const int h = rest >> 5, d = rest & 31;
    ks[ii][rest] = kb[h * HS + (i0 + ii) * D_ + d];
  }
  // stage rpe chunk 0 (swizzled); 512 float4 per i-row = 1/thread each
  const int nc = (station + CH - 1) >> 6;           // chunks of 64 j
  {
    const int jj = tid >> 3, cs = tid & 7;
    const int sl = RSL(jj, cs);
    if (nc > 0) {
      reinterpret_cast<float4*>(&rpe_s[0][0][0])[sl] =
          reinterpret_cast<const float4*>(rb0)[tid];
      reinterpret_cast<float4*>(&rpe_s[0][1][0])[sl] =
          reinterpret_cast<const float4*>(rb1)[tid];
    }
  }
  __syncthreads();

  // hoisted K fragments for this wave's head (16 VGPRs)
  const float4 k0a = *reinterpret_cast<const float4*>(&ks[0][w * D_ + dq * 8]);
  const float4 k0b = *reinterpret_cast<const float4*>(&ks[0][w * D_ + dq * 8 + 4]);
  const float4 k1a = *reinterpret_cast<const float4*>(&ks[1][w * D_ + dq * 8]);
  const float4 k1b = *reinterpret_cast<const float4*>(&ks[1][w * D_ + dq * 8 + 4]);
  const float* qh = qb + w * HS;
  float* ph0 = &p_smem[0][w][0];
  float* ph1 = &p_smem[1][w][0];

  // ---- scores: chunked over j; all waves consume the staged chunk ----
  for (int c = 0; c < nc; ++c) {
    if (c) __syncthreads();                         // chunk c staged; c-1 reads done
    if (c + 1 < nc) {                               // stage next chunk
      const int jj = tid >> 3, cs = tid & 7;
      const int sl = RSL(jj, cs);
      const int buf = (c + 1) & 1;
      reinterpret_cast<float4*>(&rpe_s[buf][0][0])[sl] =
          reinterpret_cast<const float4*>(rb0 + (c + 1) * CH * D_)[tid];
      reinterpret_cast<float4*>(&rpe_s[buf][1][0])[sl] =
          reinterpret_cast<const float4*>(rb1 + (c + 1) * CH * D_)[tid];
    }
    const float4* rs0 = reinterpret_cast<const float4*>(&rpe_s[c & 1][0][0]);
    const float4* rs1 = reinterpret_cast<const float4*>(&rpe_s[c & 1][1][0]);
    #pragma unroll
    for (int p = 0; p < CH / 16; ++p) {
      const int jl = p * 16 + j4;                   // local j in chunk
      const int j  = c * CH + jl;                   // j <= 511 always
      const float4 q0 = *reinterpret_cast<const float4*>(qh + j * D_ + dq * 8);
      const float4 q1 = *reinterpret_cast<const float4*>(qh + j * D_ + dq * 8 + 4);
      const float4 ra0 = rs0[RSL(jl, 2 * dq)];
      const float4 ra1 = rs0[RSL(jl, 2 * dq + 1)];
      const float4 rb0v = rs1[RSL(jl, 2 * dq)];
      const float4 rb1v = rs1[RSL(jl, 2 * dq + 1)];
      float s0 = q0.x * k0a.x * ra0.x;
      s0 = fmaf(q0.y * k0a.y, ra0.y, s0);
      s0 = fmaf(q0.z * k0a.z, ra0.z, s0);
      s0 = fmaf(q0.w * k0a.w, ra0.w, s0);
      s0 = fmaf(q1.x * k0b.x, ra1.x, s0);
      s0 = fmaf(q1.y * k0b.y, ra1.y, s0);
      s0 = fmaf(q1.z * k0b.z, ra1.z, s0);
      s0 = fmaf(q1.w * k0b.w, ra1.w, s0);
      float s1 = q0.x * k1a.x * rb0v.x;
      s1 = fmaf(q0.y * k1a.y, rb0v.y, s1);
      s1 = fmaf(q0.z * k1a.z, rb0v.z, s1);
      s1 = fmaf(q0.w * k1a.w, rb0v.w, s1);
      s1 = fmaf(q1.x * k1b.x, rb1v.x, s1);
      s1 = fmaf(q1.y * k1b.y, rb1v.y, s1);
      s1 = fmaf(q1.z * k1b.z, rb1v.z, s1);
      s1 = fmaf(q1.w * k1b.w, rb1v.w, s1);
      s0 = red4(s0);
      s1 = red4(s1);
      if (dq == 0 && j < station) { ph0[j] = s0; ph1[j] = s1; }
    }
  }
  // diagonal cells j == i0+ii when beyond station (lanes 0..3 of each wave;
  // rpe/q from global -- once per block per (head, ii))
  if (j4 == 0) {
    if (dx0) {
      const int i = i0;
      const float4 r0 = *reinterpret_cast<const float4*>(rb0 + i * D_ + dq * 8);
      const float4 r1 = *reinterpret_cast<const float4*>(rb0 + i * D_ + dq * 8 + 4);
      const float4 q0 = *reinterpret_cast<const float4*>(qh + i * D_ + dq * 8);
      const float4 q1 = *reinterpret_cast<const float4*>(qh + i * D_ + dq * 8 + 4);
      float s = q0.x * k0a.x * r0.x;
      s = fmaf(q0.y * k0a.y, r0.y, s);
      s = fmaf(q0.z * k0a.z, r0.z, s);
      s = fmaf(q0.w * k0a.w, r0.w, s);
      s = fmaf(q1.x * k0b.x, r1.x, s);
      s = fmaf(q1.y * k0b.y, r1.y, s);
      s = fmaf(q1.z * k0b.z, r1.z, s);
      s = fmaf(q1.w * k0b.w, r1.w, s);
      s = red4(s);
      if (dq == 0) ph0[i] = s;
    }
    if (dx1) {
      const int i = i0 + 1;
      const float4 r0 = *reinterpret_cast<const float4*>(rb1 + i * D_ + dq * 8);
      const float4 r1 = *reinterpret_cast<const float4*>(rb1 + i * D_ + dq * 8 + 4);
      const float4 q0 = *reinterpret_cast<const float4*>(qh + i * D_ + dq * 8);
      const float4 q1 = *reinterpret_cast<const float4*>(qh + i * D_ + dq * 8 + 4);
      float s = q0.x * k1a.x * r0.x;
      s = fmaf(q0.y * k1a.y, r0.y, s);
      s = fmaf(q0.z * k1a.z, r0.z, s);
      s = fmaf(q0.w * k1a.w, r0.w, s);
      s = fmaf(q1.x * k1b.x, r1.x, s);
      s = fmaf(q1.y * k1b.y, r1.y, s);
      s = fmaf(q1.z * k1b.z, r1.z, s);
      s = fmaf(q1.w * k1b.w, r1.w, s);
      s = red4(s);
      if (dq == 0) ph1[i] = s;
    }
  }
  __syncthreads();

  // ---- softmax: wave w handles rows (ii=0,h=w) and (ii=1,h=w) ----
  #pragma unroll
  for (int ii = 0; ii < TI; ++ii) {
    float* pr = &p_smem[ii][w][0];
    const int ig = i0 + ii;
    const bool dxi = (ig >= station);
    float m = -1e30f;
    for (int jj = lane; jj < station; jj += 64) m = fmaxf(m, pr[jj]);
    const float dv = dxi ? pr[ig] : -1e30f;
    m = fmaxf(m, dv);
    #pragma unroll
    for (int o = 32; o; o >>= 1) m = fmaxf(m, __shfl_xor(m, o, 64));
    float sum = 0.f;
    for (int jj = lane; jj < station; jj += 64) {
      const float e = __expf(pr[jj] - m);
      pr[jj] = e;
      sum += e;
    }
    #pragma unroll
    for (int o = 32; o; o >>= 1) sum += __shfl_xor(sum, o, 64);
    if (dxi) {
      const float e = __expf(dv - m);
      sum += e;
      if (lane == 0) pr[ig] = e;
    }
    if (lane == 0) sums[ii][w] = sum;
  }
  __syncthreads();

  // ---- attn @ V: wave w owns head w; each V load feeds both i-rows ----
  float4 a0 = make_float4(0.f, 0.f, 0.f, 0.f);
  float4 a1 = make_float4(0.f, 0.f, 0.f, 0.f);
  {
    const float* vh = vb + w * HS;
    #pragma unroll 4
    for (int jb = 0; jb < station; jb += 8) {
      const int j  = jb + j8;
      const int jc = j < S_ ? j : S_ - 1;
      const float4 v4 = *reinterpret_cast<const float4*>(vh + jc * D_ + dc * 4);
      float pv0 = 0.f, pv1 = 0.f;
      if (j < station) { pv0 = ph0[j]; pv1 = ph1[j]; }
      a0.x = fmaf(pv0, v4.x, a0.x);
      a0.y = fmaf(pv0, v4.y, a0.y);
      a0.z = fmaf(pv0, v4.z, a0.z);
      a0.w = fmaf(pv0, v4.w, a0.w);
      a1.x = fmaf(pv1, v4.x, a1.x);
      a1.y = fmaf(pv1, v4.y, a1.y);
      a1.z = fmaf(pv1, v4.z, a1.z);
      a1.w = fmaf(pv1, v4.w, a1.w);
    }
  }
  // reduce over j8 groups (lane bits 3..5)
  #pragma unroll
  for (int o = 8; o <= 32; o <<= 1) {
    a0.x += __shfl_xor(a0.x, o, 64);
    a0.y += __shfl_xor(a0.y, o, 64);
    a0.z += __shfl_xor(a0.z, o, 64);
    a0.w += __shfl_xor(a0.w, o, 64);
    a1.x += __shfl_xor(a1.x, o, 64);
    a1.y += __shfl_xor(a1.y, o, 64);
    a1.z += __shfl_xor(a1.z, o, 64);
    a1.w += __shfl_xor(a1.w, o, 64);
  }
  if (j8 == 0) {
    // diagonal contributions (exactly once, post-reduction)
    if (dx0) {
      const float pv = ph0[i0];
      const float4 v4 = *reinterpret_cast<const float4*>(vb + w * HS + i0 * D_ + dc * 4);
      a0.x = fmaf(pv, v4.x, a0.x);
      a0.y = fmaf(pv, v4.y, a0.y);
      a0.z = fmaf(pv, v4.z, a0.z);
      a0.w = fmaf(pv, v4.w, a0.w);
    }
    if (dx1) {
      const float pv = ph1[i0 + 1];
      const float4 v4 = *reinterpret_cast<const float4*>(vb + w * HS + (i0 + 1) * D_ + dc * 4);
      a1.x = fmaf(pv, v4.x, a1.x);
      a1.y = fmaf(pv, v4.y, a1.y);
      a1.z = fmaf(pv, v4.z, a1.z);
      a1.w = fmaf(pv, v4.w, a1.w);
    }
    const float inv0 = 1.f / sums[0][w];
    const float inv1 = 1.f / sums[1][w];
    a0.x *= inv0; a0.y *= inv0; a0.z *= inv0; a0.w *= inv0;
    a1.x *= inv1; a1.y *= inv1; a1.z *= inv1; a1.w *= inv1;
    reinterpret_cast<float4*>(&orow[0][w * D_])[dc] = a0;
    reinterpret_cast<float4*>(&orow[1][w * D_])[dc] = a1;
  }
  __syncthreads();

  // ---- fc (thread per output column m=tid, first 4 waves) + residual + LN --
  float f0 = 0.f, f1 = 0.f;
  if (tid < DM_) {
    const float* wp = fc_w + tid;
    #pragma unroll 8
    for (int n4 = 0; n4 < HD_ / 4; ++n4) {
      const float4 o0 = reinterpret_cast<const float4*>(&orow[0][0])[n4];
      const float4 o1 = reinterpret_cast<const float4*>(&orow[1][0])[n4];
      const float w0 = wp[(4 * n4 + 0) * DM_];
      const float w1 = wp[(4 * n4 + 1) * DM_];
      const float w2 = wp[(4 * n4 + 2) * DM_];
      const float w3 = wp[(4 * n4 + 3) * DM_];
      f0 = fmaf(o0.x, w0, f0); f1 = fmaf(o1.x, w0, f1);
      f0 = fmaf(o0.y, w1, f0); f1 = fmaf(o1.y, w1, f1);
      f0 = fmaf(o0.z, w2, f0); f1 = fmaf(o1.z, w2, f1);
      f0 = fmaf(o0.w, w3, f0); f1 = fmaf(o1.w, w3, f1);
    }
    const float bias = fc_b[tid];
    f0 += bias + hid[(size_t)(b * S_ + i0) * DM_ + tid];
    f1 += bias + hid[(size_t)(b * S_ + i0 + 1) * DM_ + tid];
    float s0 = f0, s1 = f1;
    #pragma unroll
    for (int o = 32; o; o >>= 1) {
      s0 += __shfl_xor(s0, o, 64);
      s1 += __shfl_xor(s1, o, 64);
    }
    if (lane == 0) { redm[0][w] = s0; redm[1][w] = s1; }
  }
  __syncthreads();
  const float mu0 = (redm[0][0] + redm[0][1] + redm[0][2] + redm[0][3]) * (1.f / DM_);
  const float mu1 = (redm[1][0] + redm[1][1] + redm[1][2] + redm[1][3]) * (1.f / DM_);
  const float d0 = f0 - mu0, d1 = f1 - mu1;
  if (tid < DM_) {
    float s0 = d0 * d0, s1 = d1 * d1;
    #pragma unroll
    for (int o = 32; o; o >>= 1) {
      s0 += __shfl_xor(s0, o, 64);
      s1 += __shfl_xor(s1, o, 64);
    }
    if (lane == 0) { redvr[0][w] = s0; redvr[1][w] = s1; }
  }
  __syncthreads();
  if (tid < DM_) {
    const float v0 = (redvr[0][0] + redvr[0][1] + redvr[0][2] + redvr[0][3]) * (1.f / DM_);
    const float v1 = (redvr[1][0] + redvr[1][1] + redvr[1][2] + redvr[1][3]) * (1.f / DM_);
    const float lw = ln_w[tid], lb = ln_b[tid];
    out[(size_t)(b * S_ + i0) * DM_ + tid]     = d0 * rsqrtf(v0 + 1e-6f) * lw + lb;
    out[(size_t)(b * S_ + i0 + 1) * DM_ + tid] = d1 * rsqrtf(v1 + 1e-6f) * lw + lb;
  }
}

// ---------------------------------------------------------------------------
extern "C" void kernel_launch(void* const* d_in, const int* in_sizes, int n_in,
                              void* d_out, int out_size, void* d_ws, size_t ws_size,
                              hipStream_t stream) {
  const float* hid = (const float*)d_in[0];
  const float* rpe = (const float*)d_in[1];
  const float* wq  = (const float*)d_in[2];
  const float* wk  = (const float*)d_in[3];
  const float* wv  = (const float*)d_in[4];
  const float* fcw = (const float*)d_in[5];
  const float* fcb = (const float*)d_in[6];
  const float* lnw = (const float*)d_in[7];
  const float* lnb = (const float*)d_in[8];
  const int* station = (const int*)d_in[9];
  float* out = (float*)d_out;

  const size_t per = (size_t)B_ * H_ * S_ * D_;   // 262144 floats
  float* q_ws = (float*)d_ws;
  float* k_ws = q_ws + per;
  float* v_ws = k_ws + per;

  dim3 gA(B_ * S_ / NROW, 3);
  qkv_kernel<<<gA, 256, 0, stream>>>(hid, wq, wk, wv, q_ws, k_ws, v_ws);
  attn_fused_kernel<<<B_ * S_ / TI, 512, 0, stream>>>(
      rpe, q_ws, k_ws, v_ws, station, fcw, fcb, hid, lnw, lnb, out);
}